// Round 6
// baseline (300.548 us; speedup 1.0000x reference)
//
#include <hip/hip_runtime.h>
#include <math.h>

#define BATCH 8
#define CX 256
#define TC 512
#define CIN 768
#define HW_TOT 1024
#define NH 4
#define CHD 64

typedef __attribute__((ext_vector_type(8))) short short8;
typedef __attribute__((ext_vector_type(4))) short s4v;
typedef __attribute__((ext_vector_type(4))) float floatx4;

// round-to-nearest-even f32 -> bf16
static __device__ __forceinline__ short f2bf(float f) {
    union { float f; unsigned u; } c; c.f = f;
    unsigned r = (c.u + 0x7fffu + ((c.u >> 16) & 1u)) >> 16;
    return (short)r;
}

// ---------------------------------------------------------------------------
// Kernel 1: full GroupNorm -> per-(b,c) scale/shift in ONE kernel.
// Block = (b,g), 4 waves x 6 rows, float4 coalesced. Also zeroes the attn
// split counters (this kernel runs 3 launches before attn on the stream).
// Grid 256 x 256.
// ---------------------------------------------------------------------------
__global__ __launch_bounds__(256)
void gn_kernel(const float* __restrict__ x, const float* __restrict__ tf,
               const float* __restrict__ gamma, const float* __restrict__ beta,
               float* __restrict__ scale, float* __restrict__ shift,
               unsigned* __restrict__ cnt) {
    const int b = blockIdx.x >> 5;
    const int g = blockIdx.x & 31;
    const int t = threadIdx.x;
    const int w = t >> 6, lane = t & 63;
    if (t < 2) cnt[blockIdx.x * 2 + t] = 0u;

    float s = 0.f, ss = 0.f;
    #pragma unroll
    for (int rr = 0; rr < 6; rr++) {
        const int row = w * 6 + rr;          // 0..23
        const int cg = g * 24 + row;
        if (cg < CX) {
            const float4* p = (const float4*)(x + ((size_t)b * CX + cg) * HW_TOT);
            #pragma unroll
            for (int i = 0; i < 4; i++) {
                float4 v = p[lane + 64 * i];
                s += v.x + v.y + v.z + v.w;
                ss += v.x * v.x + v.y * v.y + v.z * v.z + v.w * v.w;
            }
        } else {
            float v = tf[b * TC + cg - CX];  // broadcast; 64 lanes x 16 = 1024x
            s += 16.f * v;
            ss += 16.f * v * v;
        }
    }
    #pragma unroll
    for (int d = 1; d < 64; d <<= 1) {
        s += __shfl_xor(s, d);
        ss += __shfl_xor(ss, d);
    }
    __shared__ float rs_[4], rss_[4];
    if (lane == 0) { rs_[w] = s; rss_[w] = ss; }
    __syncthreads();
    const float S  = rs_[0] + rs_[1] + rs_[2] + rs_[3];
    const float SS = rss_[0] + rss_[1] + rss_[2] + rss_[3];
    const float inv_n = 1.f / (24 * 1024);
    const float mean = S * inv_n;
    const float var = SS * inv_n - mean * mean;
    const float r = rsqrtf(var + 1e-6f);
    if (t < 24) {
        int cg = g * 24 + t;
        float sc = gamma[cg] * r;
        scale[b * CIN + cg] = sc;
        shift[b * CIN + cg] = beta[cg] - mean * sc;
    }
}

// ---------------------------------------------------------------------------
// Kernel 2: merged prep: hnT transpose (blocks 0-255), W transpose (256-267),
// text contribution (268-363). (unchanged, proven)
// ---------------------------------------------------------------------------
__global__ __launch_bounds__(256)
void prep_kernel(const float* __restrict__ x, const float* __restrict__ tf,
                 const float* __restrict__ scale, const float* __restrict__ shift,
                 const float* __restrict__ W0, const float* __restrict__ W1,
                 const float* __restrict__ W2,
                 short* __restrict__ hnT, short* __restrict__ Wt,
                 float* __restrict__ tc) {
    __shared__ float hs[TC];
    __shared__ float red[4][64];
    const int bx = blockIdx.x;
    const int t = threadIdx.x;
    if (bx < 256) {
        int id = (bx & 31) * 256 + t;
        int b = id >> 10;
        const float* xb = x + (size_t)b * CX * HW_TOT + (id & 1023);
        const float* scb = scale + b * CIN;
        const float* shb = shift + b * CIN;
        short* outp = hnT + (size_t)id * CX;
        int c0base = (bx >> 5) * 32;
        for (int c0 = c0base; c0 < c0base + 32; c0 += 8) {
            short8 o;
            #pragma unroll
            for (int i = 0; i < 8; i++) {
                float v = xb[(size_t)(c0 + i) * HW_TOT];
                o[i] = f2bf(v * scb[c0 + i] + shb[c0 + i]);
            }
            *(short8*)(outp + c0) = o;
        }
    } else if (bx < 268) {
        int m = bx - 256;
        int dg = (m % 3) * 256 + t;
        int which = dg >> 8, d = dg & 255;
        const float* Wm = (which == 0) ? W0 : (which == 1) ? W1 : W2;
        int c0base = (m / 3) * 64;
        for (int c0 = c0base; c0 < c0base + 64; c0 += 8) {
            short8 o;
            #pragma unroll
            for (int i = 0; i < 8; i++) o[i] = f2bf(Wm[(size_t)(c0 + i) * CX + d]);
            *(short8*)(Wt + (size_t)dg * CX + c0) = o;
        }
    } else {
        int m = bx - 268;
        int b = m & 7, dt = m >> 3;
        int which = dt >> 2, d0 = (dt & 3) * 64;
        const float* Wm = (which == 0) ? W0 : (which == 1) ? W1 : W2;
        for (int c = t; c < TC; c += 256)
            hs[c] = tf[b * TC + c] * scale[b * CIN + CX + c] + shift[b * CIN + CX + c];
        __syncthreads();
        int td = t & 63, tq = t >> 6;
        float acc = 0.f;
        const float* wp = Wm + (size_t)(CX + tq * 128) * CX + d0 + td;
        for (int c = 0; c < 128; c++)
            acc = fmaf(hs[tq * 128 + c], wp[(size_t)c * CX], acc);
        red[tq][td] = acc;
        __syncthreads();
        if (t < 64)
            tc[b * CIN + which * CX + d0 + t] = red[0][t] + red[1][t] + red[2][t] + red[3][t];
    }
}

// ---------------------------------------------------------------------------
// Kernel 3: MFMA QKV GEMM (K=256), bf16 in / fp32 acc. (unchanged, proven)
// q,k written [b][hw][256]; v written [b][256][1024].
// ---------------------------------------------------------------------------
__global__ __launch_bounds__(256)
void qkv_gemm(const short* __restrict__ hnT, const short* __restrict__ Wt,
              const float* __restrict__ tc,
              const float* __restrict__ b0, const float* __restrict__ b1,
              const float* __restrict__ b2,
              short* __restrict__ qb, short* __restrict__ kb, short* __restrict__ vb) {
    const int hw0 = blockIdx.x * 128, dt = blockIdx.y, b = blockIdx.z;
    const int dg0 = dt * 128;
    const int which = dt >> 1;
    const bool OV = (which == 2);

    __shared__ short At[128 * 40];
    __shared__ short Bt[128 * 40];

    const int t = threadIdx.x;
    const int w = t >> 6, l = t & 63;
    const int wm = w >> 1, wn = w & 1;
    const int l15 = l & 15, q = l >> 4;

    const int srow = t >> 1, sch = (t & 1) * 16;
    const short* gA = hnT + (size_t)(b * HW_TOT + hw0 + srow) * CX + sch;
    const short* gB = Wt + (size_t)(dg0 + srow) * CX + sch;
    short* lA = At + srow * 40 + sch;
    short* lB = Bt + srow * 40 + sch;

    floatx4 acc[4][4] = {};
    for (int k0 = 0; k0 < CX; k0 += 32) {
        __syncthreads();
        *(short8*)lA       = *(const short8*)(gA + k0);
        *(short8*)(lA + 8) = *(const short8*)(gA + k0 + 8);
        *(short8*)lB       = *(const short8*)(gB + k0);
        *(short8*)(lB + 8) = *(const short8*)(gB + k0 + 8);
        __syncthreads();
        const short* aBase = OV ? Bt : At;
        const short* bBase = OV ? At : Bt;
        short8 af[4], bf[4];
        #pragma unroll
        for (int mt = 0; mt < 4; mt++)
            af[mt] = *(const short8*)(aBase + (wm * 64 + mt * 16 + l15) * 40 + q * 8);
        #pragma unroll
        for (int nt = 0; nt < 4; nt++)
            bf[nt] = *(const short8*)(bBase + (wn * 64 + nt * 16 + l15) * 40 + q * 8);
        #pragma unroll
        for (int mt = 0; mt < 4; mt++)
            #pragma unroll
            for (int nt = 0; nt < 4; nt++)
                acc[mt][nt] = __builtin_amdgcn_mfma_f32_16x16x32_bf16(
                    af[mt], bf[nt], acc[mt][nt], 0, 0, 0);
    }

    __syncthreads();
    const float* bias = (which == 0) ? b0 : (which == 1) ? b1 : b2;
    short* epi = At + w * (16 * 72);

    float colAdd[4];
    if (!OV) {
        #pragma unroll
        for (int nt = 0; nt < 4; nt++) {
            int cl = (dt & 1) * 128 + wn * 64 + l15 + nt * 16;
            colAdd[nt] = bias[cl] + tc[b * CIN + which * CX + cl];
        }
    }
    const int row_l = l >> 2, ch = l & 3;
    #pragma unroll
    for (int mt = 0; mt < 4; mt++) {
        #pragma unroll
        for (int rr = 0; rr < 4; rr++) {
            float radd = 0.f;
            if (OV) {
                int rl = (dt & 1) * 128 + wm * 64 + mt * 16 + q * 4 + rr;
                radd = bias[rl] + tc[b * CIN + 2 * CX + rl];
            }
            #pragma unroll
            for (int nt = 0; nt < 4; nt++) {
                float val = acc[mt][nt][rr] + (OV ? radd : colAdd[nt]);
                epi[(q * 4 + rr) * 72 + l15 + nt * 16] = f2bf(val);
            }
        }
        short8 v0 = *(const short8*)(epi + row_l * 72 + ch * 16);
        short8 v1 = *(const short8*)(epi + row_l * 72 + ch * 16 + 8);
        if (!OV) {
            short* outp = (which == 0) ? qb : kb;
            size_t off = (size_t)(b * HW_TOT + hw0 + wm * 64 + mt * 16 + row_l) * CX
                       + (dt & 1) * 128 + wn * 64 + ch * 16;
            *(short8*)(outp + off) = v0;
            *(short8*)(outp + off + 8) = v1;
        } else {
            size_t off = (size_t)(b * CX + (dt & 1) * 128 + wm * 64 + mt * 16 + row_l) * HW_TOT
                       + hw0 + wn * 64 + ch * 16;
            *(short8*)(vb + off) = v0;
            *(short8*)(vb + off + 8) = v1;
        }
    }
}

// ---------------------------------------------------------------------------
// Kernel 4: split-j flash attention + in-kernel split combine (split-k fixup
// pattern: write partial, release fence, counter atomicAdd; second finisher
// acquire-fences, reads the other partial, adds residual, writes out).
// Fixed-max softmax (exact). Grid (16 qt, 32 bh, 2 split) x 256.
// ---------------------------------------------------------------------------
__global__ __launch_bounds__(256)
void attn_kernel(const short* __restrict__ qb, const short* __restrict__ kb,
                 const short* __restrict__ vb, const float* __restrict__ x,
                 float* __restrict__ opart, float* __restrict__ lpart,
                 unsigned* __restrict__ cnt, float* __restrict__ out) {
    const int qt = blockIdx.x, bh = blockIdx.y, sp = blockIdx.z;
    const int b = bh >> 2, h = bh & 3;
    const int hw0 = qt * 64;

    __shared__ short Qs[64 * 72];
    __shared__ short Ks[64 * 72];
    __shared__ short Vs[64 * 72];
    __shared__ unsigned oldv;

    const int t = threadIdx.x;
    const int w = t >> 6, l = t & 63;
    const int l15 = l & 15, q = l >> 4;
    const int srow = t >> 2, sch = (t & 3) * 16;

    {   // stage Q tile [qi][c]
        const short* gq = qb + (size_t)(b * HW_TOT + hw0 + srow) * CX + h * CHD + sch;
        *(short8*)(Qs + srow * 72 + sch)     = *(const short8*)gq;
        *(short8*)(Qs + srow * 72 + sch + 8) = *(const short8*)(gq + 8);
    }

    // prefetch first tile of this split
    short8 pk0, pk1, pv0, pv1;
    {
        const int j0 = sp * 512;
        const short* gk = kb + (size_t)(b * HW_TOT + j0 + srow) * CX + h * CHD + sch;
        pk0 = *(const short8*)gk;
        pk1 = *(const short8*)(gk + 8);
        const short* gv = vb + (size_t)(b * CX + h * CHD + srow) * HW_TOT + j0 + sch;
        pv0 = *(const short8*)gv;
        pv1 = *(const short8*)(gv + 8);
    }
    __syncthreads();
    const short8 aq0 = *(const short8*)(Qs + (w * 16 + l15) * 72 + q * 8);
    const short8 aq1 = *(const short8*)(Qs + (w * 16 + l15) * 72 + 32 + q * 8);

    floatx4 oacc[4] = {};
    float lsum = 0.f;

    for (int jj = 0; jj < 8; jj++) {
        *(short8*)(Ks + srow * 72 + sch)     = pk0;
        *(short8*)(Ks + srow * 72 + sch + 8) = pk1;
        *(short8*)(Vs + srow * 72 + sch)     = pv0;
        *(short8*)(Vs + srow * 72 + sch + 8) = pv1;
        __syncthreads();

        if (jj < 7) {
            const int j0 = sp * 512 + (jj + 1) * 64;
            const short* gk = kb + (size_t)(b * HW_TOT + j0 + srow) * CX + h * CHD + sch;
            pk0 = *(const short8*)gk;
            pk1 = *(const short8*)(gk + 8);
            const short* gv = vb + (size_t)(b * CX + h * CHD + srow) * HW_TOT + j0 + sch;
            pv0 = *(const short8*)gv;
            pv1 = *(const short8*)(gv + 8);
        }

        // S^T = K . Q^T : C[m=kj][n=qi]
        floatx4 sacc[4] = {};
        #pragma unroll
        for (int nt = 0; nt < 4; nt++) {
            short8 kf0 = *(const short8*)(Ks + (nt * 16 + l15) * 72 + q * 8);
            short8 kf1 = *(const short8*)(Ks + (nt * 16 + l15) * 72 + 32 + q * 8);
            sacc[nt] = __builtin_amdgcn_mfma_f32_16x16x32_bf16(kf0, aq0, sacc[nt], 0, 0, 0);
            sacc[nt] = __builtin_amdgcn_mfma_f32_16x16x32_bf16(kf1, aq1, sacc[nt], 0, 0, 0);
        }

        // fixed-max softmax: p = exp(s*0.125 - 10); accumulate per-lane l
        short8 pf[2];
        #pragma unroll
        for (int nt = 0; nt < 4; nt++)
            #pragma unroll
            for (int r = 0; r < 4; r++) {
                float e = __expf(fmaf(sacc[nt][r], 0.125f, -10.f));
                lsum += e;
                pf[nt >> 1][(nt & 1) * 4 + r] = f2bf(e);
            }

        // O^T += V^T . P : A=V (concat reads), B=P from registers
        #pragma unroll
        for (int ct = 0; ct < 4; ct++) {
            const short* vr = Vs + (ct * 16 + l15) * 72;
            #pragma unroll
            for (int kcc = 0; kcc < 2; kcc++) {
                s4v vlo = *(const s4v*)(vr + kcc * 32 + q * 4);
                s4v vhi = *(const s4v*)(vr + kcc * 32 + 16 + q * 4);
                short8 vf = __builtin_shufflevector(vlo, vhi, 0, 1, 2, 3, 4, 5, 6, 7);
                oacc[ct] = __builtin_amdgcn_mfma_f32_16x16x32_bf16(vf, pf[kcc], oacc[ct], 0, 0, 0);
            }
        }
        __syncthreads();
    }

    // full row-sum for this split (every lane ends with its qi's sum)
    lsum += __shfl_xor(lsum, 16);
    lsum += __shfl_xor(lsum, 32);

    // write partial o (C-layout) and partial l
    float* op = opart + ((size_t)(sp * BATCH + b) * CX) * HW_TOT;
    #pragma unroll
    for (int ct = 0; ct < 4; ct++)
        #pragma unroll
        for (int r = 0; r < 4; r++) {
            int c = h * CHD + ct * 16 + q * 4 + r;
            op[(size_t)c * HW_TOT + hw0 + w * 16 + l15] = oacc[ct][r];
        }
    if (q == 0)
        lpart[(size_t)(sp * 32 + bh) * HW_TOT + hw0 + w * 16 + l15] = lsum;

    // release: make this block's writes device-visible, then bump counter
    __threadfence();
    __syncthreads();
    if (t == 0) oldv = atomicAdd(&cnt[qt * 32 + bh], 1u);
    __syncthreads();
    if (oldv == 0) return;    // first finisher exits; second combines

    __threadfence();          // acquire: other split's writes now visible
    const int osp = 1 - sp;
    const float* oo = opart + ((size_t)(osp * BATCH + b) * CX) * HW_TOT;
    const float lo = lpart[(size_t)(osp * 32 + bh) * HW_TOT + hw0 + w * 16 + l15];
    const float rinv = 1.f / (lsum + lo);
    #pragma unroll
    for (int ct = 0; ct < 4; ct++)
        #pragma unroll
        for (int r = 0; r < 4; r++) {
            int c = h * CHD + ct * 16 + q * 4 + r;
            size_t idx = (size_t)(b * CX + c) * HW_TOT + hw0 + w * 16 + l15;
            out[idx] = x[idx] + (oacc[ct][r] + oo[(size_t)c * HW_TOT + hw0 + w * 16 + l15]) * rinv;
        }
}

// ---------------------------------------------------------------------------
extern "C" void kernel_launch(void* const* d_in, const int* in_sizes, int n_in,
                              void* d_out, int out_size, void* d_ws, size_t ws_size,
                              hipStream_t stream) {
    (void)in_sizes; (void)n_in; (void)out_size; (void)ws_size;
    const float* x     = (const float*)d_in[0];
    const float* tf    = (const float*)d_in[1];
    const float* gamma = (const float*)d_in[2];
    const float* beta  = (const float*)d_in[3];
    const float* W0 = (const float*)d_in[4];
    const float* b0 = (const float*)d_in[5];
    const float* W1 = (const float*)d_in[6];
    const float* b1 = (const float*)d_in[7];
    const float* W2 = (const float*)d_in[8];
    const float* b2 = (const float*)d_in[9];

    char* ws = (char*)d_ws;
    float* scale  = (float*)(ws);                 // 24576 B
    float* shift  = (float*)(ws + 24576);         // 24576 B
    float* tcb    = (float*)(ws + 49152);         // 24576 B
    short* Wt     = (short*)(ws + 73728);         // 393216 B
    short* hnT    = (short*)(ws + 466944);        // 4 MiB
    short* qb     = (short*)(ws + 4661248);       // 4 MiB
    short* kb     = (short*)(ws + 8855552);       // 4 MiB
    short* vb     = (short*)(ws + 13049856);      // 4 MiB
    float* opart  = (float*)(ws + 17244160);      // 16 MiB (2 splits)
    float* lpart  = (float*)(ws + 34021376);      // 256 KiB (2 splits)
    unsigned* cnt = (unsigned*)(ws + 34283520);   // 2 KiB (512 counters)

    hipLaunchKernelGGL(gn_kernel, dim3(256), dim3(256), 0, stream,
                       x, tf, gamma, beta, scale, shift, cnt);
    hipLaunchKernelGGL(prep_kernel, dim3(364), dim3(256), 0, stream,
                       x, tf, scale, shift, W0, W1, W2, hnT, Wt, tcb);
    hipLaunchKernelGGL(qkv_gemm, dim3(8, 6, BATCH), dim3(256), 0, stream,
                       hnT, Wt, tcb, b0, b1, b2, qb, kb, vb);
    hipLaunchKernelGGL(attn_kernel, dim3(16, 32, 2), dim3(256), 0, stream,
                       qb, kb, vb, x, opart, lpart, cnt, (float*)d_out);
}

// Round 7
// 128.334 us; speedup vs baseline: 2.3419x; 2.3419x over previous
//
#include <hip/hip_runtime.h>
#include <math.h>

#define BATCH 8
#define CX 256
#define TC 512
#define CIN 768
#define HW_TOT 1024
#define NH 4
#define CHD 64

typedef __attribute__((ext_vector_type(8))) short short8;
typedef __attribute__((ext_vector_type(4))) short s4v;
typedef __attribute__((ext_vector_type(4))) float floatx4;

// round-to-nearest-even f32 -> bf16
static __device__ __forceinline__ short f2bf(float f) {
    union { float f; unsigned u; } c; c.f = f;
    unsigned r = (c.u + 0x7fffu + ((c.u >> 16) & 1u)) >> 16;
    return (short)r;
}

// ---------------------------------------------------------------------------
// Kernel 1: full GroupNorm -> per-(b,c) scale/shift in ONE kernel.
// Block = (b,g), 4 waves x 6 rows, float4 coalesced. Grid 256 x 256.
// ---------------------------------------------------------------------------
__global__ __launch_bounds__(256)
void gn_kernel(const float* __restrict__ x, const float* __restrict__ tf,
               const float* __restrict__ gamma, const float* __restrict__ beta,
               float* __restrict__ scale, float* __restrict__ shift) {
    const int b = blockIdx.x >> 5;
    const int g = blockIdx.x & 31;
    const int t = threadIdx.x;
    const int w = t >> 6, lane = t & 63;

    float s = 0.f, ss = 0.f;
    #pragma unroll
    for (int rr = 0; rr < 6; rr++) {
        const int row = w * 6 + rr;          // 0..23
        const int cg = g * 24 + row;
        if (cg < CX) {
            const float4* p = (const float4*)(x + ((size_t)b * CX + cg) * HW_TOT);
            #pragma unroll
            for (int i = 0; i < 4; i++) {
                float4 v = p[lane + 64 * i];
                s += v.x + v.y + v.z + v.w;
                ss += v.x * v.x + v.y * v.y + v.z * v.z + v.w * v.w;
            }
        } else {
            float v = tf[b * TC + cg - CX];  // broadcast; 64 lanes x 16 = 1024x
            s += 16.f * v;
            ss += 16.f * v * v;
        }
    }
    #pragma unroll
    for (int d = 1; d < 64; d <<= 1) {
        s += __shfl_xor(s, d);
        ss += __shfl_xor(ss, d);
    }
    __shared__ float rs_[4], rss_[4];
    if (lane == 0) { rs_[w] = s; rss_[w] = ss; }
    __syncthreads();
    const float S  = rs_[0] + rs_[1] + rs_[2] + rs_[3];
    const float SS = rss_[0] + rss_[1] + rss_[2] + rss_[3];
    const float inv_n = 1.f / (24 * 1024);
    const float mean = S * inv_n;
    const float var = SS * inv_n - mean * mean;
    const float r = rsqrtf(var + 1e-6f);
    if (t < 24) {
        int cg = g * 24 + t;
        float sc = gamma[cg] * r;
        scale[b * CIN + cg] = sc;
        shift[b * CIN + cg] = beta[cg] - mean * sc;
    }
}

// ---------------------------------------------------------------------------
// Kernel 2: merged prep: hnT transpose (blocks 0-255), W transpose (256-267),
// text contribution (268-363). (unchanged, proven)
// ---------------------------------------------------------------------------
__global__ __launch_bounds__(256)
void prep_kernel(const float* __restrict__ x, const float* __restrict__ tf,
                 const float* __restrict__ scale, const float* __restrict__ shift,
                 const float* __restrict__ W0, const float* __restrict__ W1,
                 const float* __restrict__ W2,
                 short* __restrict__ hnT, short* __restrict__ Wt,
                 float* __restrict__ tc) {
    __shared__ float hs[TC];
    __shared__ float red[4][64];
    const int bx = blockIdx.x;
    const int t = threadIdx.x;
    if (bx < 256) {
        int id = (bx & 31) * 256 + t;
        int b = id >> 10;
        const float* xb = x + (size_t)b * CX * HW_TOT + (id & 1023);
        const float* scb = scale + b * CIN;
        const float* shb = shift + b * CIN;
        short* outp = hnT + (size_t)id * CX;
        int c0base = (bx >> 5) * 32;
        for (int c0 = c0base; c0 < c0base + 32; c0 += 8) {
            short8 o;
            #pragma unroll
            for (int i = 0; i < 8; i++) {
                float v = xb[(size_t)(c0 + i) * HW_TOT];
                o[i] = f2bf(v * scb[c0 + i] + shb[c0 + i]);
            }
            *(short8*)(outp + c0) = o;
        }
    } else if (bx < 268) {
        int m = bx - 256;
        int dg = (m % 3) * 256 + t;
        int which = dg >> 8, d = dg & 255;
        const float* Wm = (which == 0) ? W0 : (which == 1) ? W1 : W2;
        int c0base = (m / 3) * 64;
        for (int c0 = c0base; c0 < c0base + 64; c0 += 8) {
            short8 o;
            #pragma unroll
            for (int i = 0; i < 8; i++) o[i] = f2bf(Wm[(size_t)(c0 + i) * CX + d]);
            *(short8*)(Wt + (size_t)dg * CX + c0) = o;
        }
    } else {
        int m = bx - 268;
        int b = m & 7, dt = m >> 3;
        int which = dt >> 2, d0 = (dt & 3) * 64;
        const float* Wm = (which == 0) ? W0 : (which == 1) ? W1 : W2;
        for (int c = t; c < TC; c += 256)
            hs[c] = tf[b * TC + c] * scale[b * CIN + CX + c] + shift[b * CIN + CX + c];
        __syncthreads();
        int td = t & 63, tq = t >> 6;
        float acc = 0.f;
        const float* wp = Wm + (size_t)(CX + tq * 128) * CX + d0 + td;
        for (int c = 0; c < 128; c++)
            acc = fmaf(hs[tq * 128 + c], wp[(size_t)c * CX], acc);
        red[tq][td] = acc;
        __syncthreads();
        if (t < 64)
            tc[b * CIN + which * CX + d0 + t] = red[0][t] + red[1][t] + red[2][t] + red[3][t];
    }
}

// ---------------------------------------------------------------------------
// Kernel 3: MFMA QKV GEMM (K=256), bf16 in / fp32 acc. (unchanged, proven)
// q,k written [b][hw][256]; v written [b][256][1024].
// ---------------------------------------------------------------------------
__global__ __launch_bounds__(256)
void qkv_gemm(const short* __restrict__ hnT, const short* __restrict__ Wt,
              const float* __restrict__ tc,
              const float* __restrict__ b0, const float* __restrict__ b1,
              const float* __restrict__ b2,
              short* __restrict__ qb, short* __restrict__ kb, short* __restrict__ vb) {
    const int hw0 = blockIdx.x * 128, dt = blockIdx.y, b = blockIdx.z;
    const int dg0 = dt * 128;
    const int which = dt >> 1;
    const bool OV = (which == 2);

    __shared__ short At[128 * 40];
    __shared__ short Bt[128 * 40];

    const int t = threadIdx.x;
    const int w = t >> 6, l = t & 63;
    const int wm = w >> 1, wn = w & 1;
    const int l15 = l & 15, q = l >> 4;

    const int srow = t >> 1, sch = (t & 1) * 16;
    const short* gA = hnT + (size_t)(b * HW_TOT + hw0 + srow) * CX + sch;
    const short* gB = Wt + (size_t)(dg0 + srow) * CX + sch;
    short* lA = At + srow * 40 + sch;
    short* lB = Bt + srow * 40 + sch;

    floatx4 acc[4][4] = {};
    for (int k0 = 0; k0 < CX; k0 += 32) {
        __syncthreads();
        *(short8*)lA       = *(const short8*)(gA + k0);
        *(short8*)(lA + 8) = *(const short8*)(gA + k0 + 8);
        *(short8*)lB       = *(const short8*)(gB + k0);
        *(short8*)(lB + 8) = *(const short8*)(gB + k0 + 8);
        __syncthreads();
        const short* aBase = OV ? Bt : At;
        const short* bBase = OV ? At : Bt;
        short8 af[4], bf[4];
        #pragma unroll
        for (int mt = 0; mt < 4; mt++)
            af[mt] = *(const short8*)(aBase + (wm * 64 + mt * 16 + l15) * 40 + q * 8);
        #pragma unroll
        for (int nt = 0; nt < 4; nt++)
            bf[nt] = *(const short8*)(bBase + (wn * 64 + nt * 16 + l15) * 40 + q * 8);
        #pragma unroll
        for (int mt = 0; mt < 4; mt++)
            #pragma unroll
            for (int nt = 0; nt < 4; nt++)
                acc[mt][nt] = __builtin_amdgcn_mfma_f32_16x16x32_bf16(
                    af[mt], bf[nt], acc[mt][nt], 0, 0, 0);
    }

    __syncthreads();
    const float* bias = (which == 0) ? b0 : (which == 1) ? b1 : b2;
    short* epi = At + w * (16 * 72);

    float colAdd[4];
    if (!OV) {
        #pragma unroll
        for (int nt = 0; nt < 4; nt++) {
            int cl = (dt & 1) * 128 + wn * 64 + l15 + nt * 16;
            colAdd[nt] = bias[cl] + tc[b * CIN + which * CX + cl];
        }
    }
    const int row_l = l >> 2, ch = l & 3;
    #pragma unroll
    for (int mt = 0; mt < 4; mt++) {
        #pragma unroll
        for (int rr = 0; rr < 4; rr++) {
            float radd = 0.f;
            if (OV) {
                int rl = (dt & 1) * 128 + wm * 64 + mt * 16 + q * 4 + rr;
                radd = bias[rl] + tc[b * CIN + 2 * CX + rl];
            }
            #pragma unroll
            for (int nt = 0; nt < 4; nt++) {
                float val = acc[mt][nt][rr] + (OV ? radd : colAdd[nt]);
                epi[(q * 4 + rr) * 72 + l15 + nt * 16] = f2bf(val);
            }
        }
        short8 v0 = *(const short8*)(epi + row_l * 72 + ch * 16);
        short8 v1 = *(const short8*)(epi + row_l * 72 + ch * 16 + 8);
        if (!OV) {
            short* outp = (which == 0) ? qb : kb;
            size_t off = (size_t)(b * HW_TOT + hw0 + wm * 64 + mt * 16 + row_l) * CX
                       + (dt & 1) * 128 + wn * 64 + ch * 16;
            *(short8*)(outp + off) = v0;
            *(short8*)(outp + off + 8) = v1;
        } else {
            size_t off = (size_t)(b * CX + (dt & 1) * 128 + wm * 64 + mt * 16 + row_l) * HW_TOT
                       + hw0 + wn * 64 + ch * 16;
            *(short8*)(vb + off) = v0;
            *(short8*)(vb + off + 8) = v1;
        }
    }
}

// ---------------------------------------------------------------------------
// Kernel 4: split-j flash attention partial (r5-proven). Fixed-max softmax.
// Partial o/l to split-private buffers; NO in-kernel cross-split combine
// (cross-XCD fence is costlier than a kernel boundary — r6 lesson).
// Grid (16 qt, 32 bh, 2 split) x 256.
// ---------------------------------------------------------------------------
__global__ __launch_bounds__(256)
void attn_part(const short* __restrict__ qb, const short* __restrict__ kb,
               const short* __restrict__ vb,
               float* __restrict__ opart, float* __restrict__ lpart) {
    const int qt = blockIdx.x, bh = blockIdx.y, sp = blockIdx.z;
    const int b = bh >> 2, h = bh & 3;
    const int hw0 = qt * 64;

    __shared__ short Qs[64 * 72];
    __shared__ short Ks[64 * 72];
    __shared__ short Vs[64 * 72];

    const int t = threadIdx.x;
    const int w = t >> 6, l = t & 63;
    const int l15 = l & 15, q = l >> 4;
    const int srow = t >> 2, sch = (t & 3) * 16;

    {   // stage Q tile [qi][c]
        const short* gq = qb + (size_t)(b * HW_TOT + hw0 + srow) * CX + h * CHD + sch;
        *(short8*)(Qs + srow * 72 + sch)     = *(const short8*)gq;
        *(short8*)(Qs + srow * 72 + sch + 8) = *(const short8*)(gq + 8);
    }

    // prefetch first tile of this split
    short8 pk0, pk1, pv0, pv1;
    {
        const int j0 = sp * 512;
        const short* gk = kb + (size_t)(b * HW_TOT + j0 + srow) * CX + h * CHD + sch;
        pk0 = *(const short8*)gk;
        pk1 = *(const short8*)(gk + 8);
        const short* gv = vb + (size_t)(b * CX + h * CHD + srow) * HW_TOT + j0 + sch;
        pv0 = *(const short8*)gv;
        pv1 = *(const short8*)(gv + 8);
    }
    __syncthreads();
    const short8 aq0 = *(const short8*)(Qs + (w * 16 + l15) * 72 + q * 8);
    const short8 aq1 = *(const short8*)(Qs + (w * 16 + l15) * 72 + 32 + q * 8);

    floatx4 oacc[4] = {};
    float lsum = 0.f;

    for (int jj = 0; jj < 8; jj++) {
        *(short8*)(Ks + srow * 72 + sch)     = pk0;
        *(short8*)(Ks + srow * 72 + sch + 8) = pk1;
        *(short8*)(Vs + srow * 72 + sch)     = pv0;
        *(short8*)(Vs + srow * 72 + sch + 8) = pv1;
        __syncthreads();

        if (jj < 7) {
            const int j0 = sp * 512 + (jj + 1) * 64;
            const short* gk = kb + (size_t)(b * HW_TOT + j0 + srow) * CX + h * CHD + sch;
            pk0 = *(const short8*)gk;
            pk1 = *(const short8*)(gk + 8);
            const short* gv = vb + (size_t)(b * CX + h * CHD + srow) * HW_TOT + j0 + sch;
            pv0 = *(const short8*)gv;
            pv1 = *(const short8*)(gv + 8);
        }

        // S^T = K . Q^T : C[m=kj][n=qi]
        floatx4 sacc[4] = {};
        #pragma unroll
        for (int nt = 0; nt < 4; nt++) {
            short8 kf0 = *(const short8*)(Ks + (nt * 16 + l15) * 72 + q * 8);
            short8 kf1 = *(const short8*)(Ks + (nt * 16 + l15) * 72 + 32 + q * 8);
            sacc[nt] = __builtin_amdgcn_mfma_f32_16x16x32_bf16(kf0, aq0, sacc[nt], 0, 0, 0);
            sacc[nt] = __builtin_amdgcn_mfma_f32_16x16x32_bf16(kf1, aq1, sacc[nt], 0, 0, 0);
        }

        // fixed-max softmax: p = exp(s*0.125 - 10); accumulate per-lane l
        short8 pf[2];
        #pragma unroll
        for (int nt = 0; nt < 4; nt++)
            #pragma unroll
            for (int r = 0; r < 4; r++) {
                float e = __expf(fmaf(sacc[nt][r], 0.125f, -10.f));
                lsum += e;
                pf[nt >> 1][(nt & 1) * 4 + r] = f2bf(e);
            }

        // O^T += V^T . P : A=V (concat reads), B=P from registers
        #pragma unroll
        for (int ct = 0; ct < 4; ct++) {
            const short* vr = Vs + (ct * 16 + l15) * 72;
            #pragma unroll
            for (int kcc = 0; kcc < 2; kcc++) {
                s4v vlo = *(const s4v*)(vr + kcc * 32 + q * 4);
                s4v vhi = *(const s4v*)(vr + kcc * 32 + 16 + q * 4);
                short8 vf = __builtin_shufflevector(vlo, vhi, 0, 1, 2, 3, 4, 5, 6, 7);
                oacc[ct] = __builtin_amdgcn_mfma_f32_16x16x32_bf16(vf, pf[kcc], oacc[ct], 0, 0, 0);
            }
        }
        __syncthreads();
    }

    // write partial o (C-layout, coalesced over qi) and partial l
    float* op = opart + ((size_t)(sp * BATCH + b) * CX) * HW_TOT;
    #pragma unroll
    for (int ct = 0; ct < 4; ct++)
        #pragma unroll
        for (int r = 0; r < 4; r++) {
            int c = h * CHD + ct * 16 + q * 4 + r;
            op[(size_t)c * HW_TOT + hw0 + w * 16 + l15] = oacc[ct][r];
        }
    lsum += __shfl_xor(lsum, 16);
    lsum += __shfl_xor(lsum, 32);
    if (q == 0)
        lpart[(size_t)(sp * 32 + bh) * HW_TOT + hw0 + w * 16 + l15] = lsum;
}

// ---------------------------------------------------------------------------
// Kernel 5: combine split partials + residual. Grid 2048 x 256, float4.
// ---------------------------------------------------------------------------
__global__ __launch_bounds__(256)
void attn_epi(const float* __restrict__ opart, const float* __restrict__ lpart,
              const float* __restrict__ x, float* __restrict__ out) {
    const int idx = (blockIdx.x * 256 + threadIdx.x) * 4;   // [b][c][hw]
    const int b = idx >> 18, c = (idx >> 10) & 255, hw = idx & 1023;
    const int bh = b * 4 + (c >> 6);
    const size_t lo = (size_t)bh * HW_TOT + hw;
    float4 l0 = *(const float4*)(lpart + lo);
    float4 l1 = *(const float4*)(lpart + 32 * HW_TOT + lo);
    float4 o0 = *(const float4*)(opart + idx);
    float4 o1 = *(const float4*)(opart + BATCH * CX * HW_TOT + idx);
    float4 xv = *(const float4*)(x + idx);
    float4 ov;
    ov.x = xv.x + (o0.x + o1.x) / (l0.x + l1.x);
    ov.y = xv.y + (o0.y + o1.y) / (l0.y + l1.y);
    ov.z = xv.z + (o0.z + o1.z) / (l0.z + l1.z);
    ov.w = xv.w + (o0.w + o1.w) / (l0.w + l1.w);
    *(float4*)(out + idx) = ov;
}

// ---------------------------------------------------------------------------
extern "C" void kernel_launch(void* const* d_in, const int* in_sizes, int n_in,
                              void* d_out, int out_size, void* d_ws, size_t ws_size,
                              hipStream_t stream) {
    (void)in_sizes; (void)n_in; (void)out_size; (void)ws_size;
    const float* x     = (const float*)d_in[0];
    const float* tf    = (const float*)d_in[1];
    const float* gamma = (const float*)d_in[2];
    const float* beta  = (const float*)d_in[3];
    const float* W0 = (const float*)d_in[4];
    const float* b0 = (const float*)d_in[5];
    const float* W1 = (const float*)d_in[6];
    const float* b1 = (const float*)d_in[7];
    const float* W2 = (const float*)d_in[8];
    const float* b2 = (const float*)d_in[9];

    char* ws = (char*)d_ws;
    float* scale  = (float*)(ws);                 // 24576 B
    float* shift  = (float*)(ws + 24576);         // 24576 B
    float* tcb    = (float*)(ws + 49152);         // 24576 B
    short* Wt     = (short*)(ws + 73728);         // 393216 B
    short* hnT    = (short*)(ws + 466944);        // 4 MiB
    short* qb     = (short*)(ws + 4661248);       // 4 MiB
    short* kb     = (short*)(ws + 8855552);       // 4 MiB
    short* vb     = (short*)(ws + 13049856);      // 4 MiB
    float* opart  = (float*)(ws + 17244160);      // 16 MiB (2 splits)
    float* lpart  = (float*)(ws + 34021376);      // 256 KiB (2 splits)

    hipLaunchKernelGGL(gn_kernel, dim3(256), dim3(256), 0, stream,
                       x, tf, gamma, beta, scale, shift);
    hipLaunchKernelGGL(prep_kernel, dim3(364), dim3(256), 0, stream,
                       x, tf, scale, shift, W0, W1, W2, hnT, Wt, tcb);
    hipLaunchKernelGGL(qkv_gemm, dim3(8, 6, BATCH), dim3(256), 0, stream,
                       hnT, Wt, tcb, b0, b1, b2, qb, kb, vb);
    hipLaunchKernelGGL(attn_part, dim3(16, 32, 2), dim3(256), 0, stream,
                       qb, kb, vb, opart, lpart);
    hipLaunchKernelGGL(attn_epi, dim3(2048), dim3(256), 0, stream,
                       opart, lpart, x, (float*)d_out);
}